// Round 6
// baseline (98.052 us; speedup 1.0000x reference)
//
#include <hip/hip_runtime.h>
#include <math.h>

#define BB 32
#define LL 128
#define HH 512
#define MM 512
#define NM 544          // 32 x-matrices + 512 centroids
#define EPSF 1e-8f
#define CPLEN 10240     // 10 upper 32x32 tiles * 1024 floats (offdiag pre-scaled by sqrt2)
#define NCH 40          // k-chunks of 256 floats

typedef __attribute__((ext_vector_type(8))) short short8b;   // 8 bf16
typedef __attribute__((ext_vector_type(4))) float f32x4;
typedef __attribute__((ext_vector_type(16))) float f32x16;

// ---------------- ws layout (floats) ----------------
//   Cp     [544][10240]   @ 0
//   part   [40][32][512]  @ 5570560
//   normsq [544]          @ 6225920
//   hsic   [32][512]      @ 6226464
//   ids    [32] (int)     @ 6242848
#define NWS_CP    0
#define NWS_PART  5570560
#define NWS_NSQ   6225920
#define NWS_HSIC  6226464
#define NWS_IDS   6242848

__device__ __forceinline__ unsigned pack2(unsigned lo, unsigned hi) {
    return (lo >> 16) | (hi & 0xffff0000u);
}

// exact 3-plane bf16 split of 8 floats (c = p0+p1+p2 to ~2^-24 rel)
__device__ __forceinline__ void split3(const float4 lo, const float4 hi,
                                       uint4& p0, uint4& p1, uint4& p2) {
    float c[8] = {lo.x, lo.y, lo.z, lo.w, hi.x, hi.y, hi.z, hi.w};
    unsigned h[8], m[8], l[8];
#pragma unroll
    for (int i = 0; i < 8; ++i) {
        h[i] = __float_as_uint(c[i]) & 0xffff0000u;
        const float r1 = c[i] - __uint_as_float(h[i]);
        m[i] = __float_as_uint(r1) & 0xffff0000u;
        l[i] = __float_as_uint(r1 - __uint_as_float(m[i]));
    }
    p0 = make_uint4(pack2(h[0],h[1]), pack2(h[2],h[3]), pack2(h[4],h[5]), pack2(h[6],h[7]));
    p1 = make_uint4(pack2(m[0],m[1]), pack2(m[2],m[3]), pack2(m[4],m[5]), pack2(m[6],m[7]));
    p2 = make_uint4(pack2(l[0],l[1]), pack2(l[2],l[3]), pack2(l[4],l[5]), pack2(l[6],l[7]));
}

// 6 significant plane-products: hh, hm, mh, mm, hl, lh
__device__ __forceinline__ void mfma6(f32x16& d, const short8b a[3], const short8b b[3]) {
    d = __builtin_amdgcn_mfma_f32_32x32x16_bf16(a[0], b[0], d, 0, 0, 0);
    d = __builtin_amdgcn_mfma_f32_32x32x16_bf16(a[0], b[1], d, 0, 0, 0);
    d = __builtin_amdgcn_mfma_f32_32x32x16_bf16(a[1], b[0], d, 0, 0, 0);
    d = __builtin_amdgcn_mfma_f32_32x32x16_bf16(a[1], b[1], d, 0, 0, 0);
    d = __builtin_amdgcn_mfma_f32_32x32x16_bf16(a[0], b[2], d, 0, 0, 0);
    d = __builtin_amdgcn_mfma_f32_32x32x16_bf16(a[2], b[0], d, 0, 0, 0);
}

// flat index of G[a][b] inside a 32x32 tile, per verified 32x32 C/D layout
// (col=lane&31, row=(reg&3)+8*(reg>>2)+4*(lane>>5)); writer stores reg-quad c
// at (c*2+hi)*128 + col*4 + q.
__device__ __forceinline__ int flatAB(int a, int b) {
    return ((a >> 3) * 2 + ((a >> 2) & 1)) * 128 + b * 4 + (a & 3);
}

// upper-tile index for i<=j, order (0,0),(0,1),(0,2),(0,3),(1,1),...
__device__ __forceinline__ int Tix(int i, int j) {
    return i * (7 - i) / 2 + j;
}

// =====================================================================
// K1: barrier-free centered Gram. 544 blocks x 256 threads.
// Wave w owns k-range [128w, 128w+128): 8 steps of k=16, staging into its
// private 12 KB LDS slice (per-wave in-order LDS => no __syncthreads in
// the main loop). Epilogue: chain-reduce 4 partial Grams in LDS, double-
// center, sqrt2-scale offdiag tiles, store upper triangle + ||C||^2.
// =====================================================================
__global__ __launch_bounds__(256, 2)
void gram_nb(const float* __restrict__ x,
             const float* __restrict__ cent,
             float* __restrict__ Cp,
             float* __restrict__ normsq)
{
    __shared__ union {
        uint4 stage[4][3][2][128];   // [wave][plane][k-octet][row], 48 KB
        float buf[12288];            // epilogue: raw Gram, 10 tiles x 1024
    } sm;
    __shared__ float rmv[128];
    __shared__ float red[256];
    __shared__ float gmsh;

    const int tid  = threadIdx.x;
    const int lane = tid & 63;
    const int wid  = tid >> 6;
    const int n    = blockIdx.x;
    const float* Amat = (n < BB) ? (x + (size_t)n * LL * HH)
                                 : (cent + (size_t)(n - BB) * LL * HH);

    const int o   = lane & 1;     // k-octet within k-16
    const int r2  = lane >> 1;    // row group 0..31 (rows 32p + r2)
    const int kw  = wid * 128;    // wave's k-base

    f32x16 acc[10];
#pragma unroll
    for (int g = 0; g < 10; ++g)
#pragma unroll
        for (int q = 0; q < 16; ++q) acc[g][q] = 0.f;

    uint4* SW = &sm.stage[wid][0][0][0];   // wave-private: [(pl*2+o)*128 + r]

    // prefetch step 0
    float4 v0[4], v1[4];
#pragma unroll
    for (int p = 0; p < 4; ++p) {
        const float* rp = Amat + (size_t)(32 * p + r2) * HH + kw + o * 8;
        v0[p] = *(const float4*)rp;
        v1[p] = *(const float4*)(rp + 4);
    }

    for (int t = 0; t < 8; ++t) {
        // ---- split + write step t into private slice ----
#pragma unroll
        for (int p = 0; p < 4; ++p) {
            uint4 q0, q1, q2;
            split3(v0[p], v1[p], q0, q1, q2);
            const int r = 32 * p + r2;
            SW[(0 * 2 + o) * 128 + r] = q0;
            SW[(1 * 2 + o) * 128 + r] = q1;
            SW[(2 * 2 + o) * 128 + r] = q2;
        }
        // ---- prefetch step t+1 (redundant reload on last iter) ----
        const int kn = kw + ((t < 7) ? (t + 1) * 16 : 112);
#pragma unroll
        for (int p = 0; p < 4; ++p) {
            const float* rp = Amat + (size_t)(32 * p + r2) * HH + kn + o * 8;
            v0[p] = *(const float4*)rp;
            v1[p] = *(const float4*)(rp + 4);
        }
        // ---- read fragments (RAW on own writes; in-order LDS) ----
        const int fo = lane >> 5, frr = lane & 31;
        short8b fr[4][3];
#pragma unroll
        for (int s = 0; s < 4; ++s)
#pragma unroll
            for (int pl = 0; pl < 3; ++pl) {
                uint4 u = SW[(pl * 2 + fo) * 128 + s * 32 + frr];
                fr[s][pl] = *(const short8b*)&u;
            }
        // ---- 10 upper tiles x 6 plane-products ----
        mfma6(acc[0], fr[0], fr[0]);
        mfma6(acc[1], fr[0], fr[1]);
        mfma6(acc[4], fr[1], fr[1]);
        mfma6(acc[2], fr[0], fr[2]);
        mfma6(acc[5], fr[1], fr[2]);
        mfma6(acc[7], fr[2], fr[2]);
        mfma6(acc[3], fr[0], fr[3]);
        mfma6(acc[6], fr[1], fr[3]);
        mfma6(acc[8], fr[2], fr[3]);
        mfma6(acc[9], fr[3], fr[3]);
    }

    __syncthreads();   // all waves done with staging; stage becomes buf

    // ---- chain-reduce the 4 wave-partials into buf ----
    const int hi  = lane >> 5, col = lane & 31;
#pragma unroll
    for (int w = 0; w < 4; ++w) {
        if (wid == w) {
#pragma unroll
            for (int g = 0; g < 10; ++g)
#pragma unroll
                for (int c = 0; c < 4; ++c) {
                    const int idx = g * 1024 + (c * 2 + hi) * 128 + col * 4;
                    f32x4 a4;
                    a4[0] = acc[g][c * 4 + 0];
                    a4[1] = acc[g][c * 4 + 1];
                    a4[2] = acc[g][c * 4 + 2];
                    a4[3] = acc[g][c * 4 + 3];
                    if (w > 0) {
                        const f32x4 old = *(const f32x4*)&sm.buf[idx];
                        a4[0] += old[0]; a4[1] += old[1];
                        a4[2] += old[2]; a4[3] += old[3];
                    }
                    *(f32x4*)&sm.buf[idx] = a4;
                }
        }
        __syncthreads();
    }

    // ---- row sums of raw G (for double-centering) ----
    float s = 0.f;
    if (tid < 128) {
        const int i = tid >> 5, ri = tid & 31;
#pragma unroll
        for (int j = 0; j < 4; ++j) {
            if (j >= i) {
                const int g = Tix(i, j);
#pragma unroll
                for (int b = 0; b < 32; ++b)
                    s += sm.buf[g * 1024 + flatAB(ri, b)];
            } else {
                const int g = Tix(j, i);
#pragma unroll
                for (int a = 0; a < 32; ++a)
                    s += sm.buf[g * 1024 + flatAB(a, ri)];
            }
        }
        rmv[tid] = s * (1.f / 128.f);
    }
    red[tid] = (tid < 128) ? s : 0.f;
    __syncthreads();
    for (int s2 = 128; s2 > 0; s2 >>= 1) {
        if (tid < s2) red[tid] += red[tid + s2];
        __syncthreads();
    }
    if (tid == 0) gmsh = red[0] * (1.f / 16384.f);
    __syncthreads();
    const float gm = gmsh;

    // ---- center + sqrt2-scale + store; ||C||^2 ----
    // e = k*256 + tid  =>  tile g = k, rem = tid (static per unrolled k)
    const int b  = tid & 31;
    const int c2 = tid >> 5;               // c*2+hi
    const int ar = (c2 >> 1) * 8 + (c2 & 1) * 4;   // row base 8c+4hi
    float nsq = 0.f;
    float* dstn = Cp + (size_t)n * CPLEN;
    static const int TI[10] = {0,0,0,0,1,1,1,2,2,3};
    static const int TJ[10] = {0,1,2,3,1,2,3,2,3,3};
#pragma unroll
    for (int g = 0; g < 10; ++g) {
        const int i = TI[g], j = TJ[g];
        const float sc = (i == j) ? 1.f : 1.41421356237309505f;
        const f32x4 vv = *(const f32x4*)&sm.buf[g * 1024 + tid * 4];
        const float4 rr = *(const float4*)&rmv[i * 32 + ar];
        const float riq[4] = {rr.x, rr.y, rr.z, rr.w};
        const float cj = rmv[j * 32 + b];
        f32x4 ov;
#pragma unroll
        for (int q = 0; q < 4; ++q) {
            const float val = (vv[q] + gm - riq[q] - cj) * sc;
            nsq = fmaf(val, val, nsq);
            ov[q] = val;
        }
        *(f32x4*)(dstn + g * 1024 + tid * 4) = ov;
    }
    __syncthreads();
    red[tid] = nsq;
    __syncthreads();
    for (int s2 = 128; s2 > 0; s2 >>= 1) {
        if (tid < s2) red[tid] += red[tid + s2];
        __syncthreads();
    }
    if (tid == 0) normsq[n] = red[0];
}

// =====================================================================
// K2: hsic partials. grid = 16 m-tiles x 40 k-chunks (640 blocks).
// =====================================================================
__global__ __launch_bounds__(256, 2)
void hsic_partial(const float* __restrict__ Cp, float* __restrict__ part)
{
    __shared__ float cx[32][260];
    __shared__ float red2[256][16];

    const int tid = threadIdx.x;
    const int bx  = blockIdx.x;
    const int mt  = bx / NCH;
    const int kc  = bx % NCH;
    const int k0  = kc * 256;

#pragma unroll
    for (int i = 0; i < 8; ++i) {
        const int idx = i * 1024 + tid * 4;
        const int b = idx >> 8, k = idx & 255;
        *(float4*)&cx[b][k] = *(const float4*)&Cp[(size_t)b * CPLEN + k0 + k];
    }
    __syncthreads();

    const int kq = tid >> 6;
    const int bg = (tid >> 3) & 7;
    const int mg = tid & 7;
    const float* cyBase = Cp + (size_t)(BB + mt * 32 + mg * 4) * CPLEN + k0 + kq * 64;

    float a[4][4];
#pragma unroll
    for (int bi = 0; bi < 4; ++bi)
#pragma unroll
        for (int mi = 0; mi < 4; ++mi) a[bi][mi] = 0.f;

    for (int kk = 0; kk < 16; ++kk) {
        float4 cy[4];
#pragma unroll
        for (int mi = 0; mi < 4; ++mi)
            cy[mi] = *(const float4*)(cyBase + (size_t)mi * CPLEN + kk * 4);
        float4 cxv[4];
#pragma unroll
        for (int bi = 0; bi < 4; ++bi)
            cxv[bi] = *(const float4*)&cx[bg + bi * 8][kq * 64 + kk * 4];
#pragma unroll
        for (int bi = 0; bi < 4; ++bi)
#pragma unroll
            for (int mi = 0; mi < 4; ++mi) {
                a[bi][mi] = fmaf(cxv[bi].x, cy[mi].x, a[bi][mi]);
                a[bi][mi] = fmaf(cxv[bi].y, cy[mi].y, a[bi][mi]);
                a[bi][mi] = fmaf(cxv[bi].z, cy[mi].z, a[bi][mi]);
                a[bi][mi] = fmaf(cxv[bi].w, cy[mi].w, a[bi][mi]);
            }
    }

#pragma unroll
    for (int e = 0; e < 16; ++e) red2[tid][e] = a[e >> 2][e & 3];
    __syncthreads();
    if (tid < 64) {
#pragma unroll
        for (int e = 0; e < 16; ++e) {
            const float s = red2[tid][e] + red2[tid + 64][e] +
                            red2[tid + 128][e] + red2[tid + 192][e];
            const int bi = e >> 2, mi = e & 3;
            const int b = ((tid >> 3) & 7) + bi * 8;
            const int m = mt * 32 + (tid & 7) * 4 + mi;
            part[((size_t)kc * 32 + b) * 512 + m] = s;
        }
    }
}

// =====================================================================
// K3: combine partials, loss matrix + per-row argmax (first occurrence)
// =====================================================================
__global__ __launch_bounds__(256)
void combine_loss(const float* __restrict__ part,
                  const float* __restrict__ normsq,
                  float* __restrict__ hsic,
                  int* __restrict__ ids,
                  float* __restrict__ out)
{
    __shared__ float rv[256];
    __shared__ int   ri[256];
    const int b = blockIdx.x;
    const int tid = threadIdx.x;
    const float vx = sqrtf(normsq[b]);

    float best = -INFINITY; int bm = 0;
    for (int m = tid; m < MM; m += 256) {
        float s = 0.f;
        for (int kc = 0; kc < NCH; ++kc)
            s += part[((size_t)kc * 32 + b) * 512 + m];
        hsic[b * MM + m] = s;
        const float vy = sqrtf(normsq[BB + m]);
        const float loss = -logf(fabsf(s) / (vx * vy) + EPSF);
        out[1 + b * MM + m] = loss;
        if (loss > best) { best = loss; bm = m; }   // ascending m keeps earliest
    }
    rv[tid] = best; ri[tid] = bm;
    __syncthreads();
    for (int s2 = 128; s2 > 0; s2 >>= 1) {
        if (tid < s2) {
            if (rv[tid + s2] > rv[tid] ||
                (rv[tid + s2] == rv[tid] && ri[tid + s2] < ri[tid])) {
                rv[tid] = rv[tid + s2]; ri[tid] = ri[tid + s2];
            }
        }
        __syncthreads();
    }
    if (tid == 0) { ids[b] = ri[0]; out[1 + BB * MM + b] = (float)ri[0]; }
}

// =====================================================================
// K4: scalar loss via gather identity hsic2[b,c] = hsic[b, idx[c]]
// =====================================================================
__global__ __launch_bounds__(1024)
void scalar_loss(const float* __restrict__ hsic,
                 const float* __restrict__ normsq,
                 const int* __restrict__ ids,
                 float* __restrict__ out)
{
    __shared__ float red[1024];
    const int tid = threadIdx.x;
    const int b = tid >> 5, c = tid & 31;
    const int m = ids[c];
    red[tid] = fabsf(hsic[b * MM + m]) /
               (sqrtf(normsq[b]) * sqrtf(normsq[BB + m]));
    __syncthreads();
    for (int s = 512; s > 0; s >>= 1) {
        if (tid < s) red[tid] += red[tid + s];
        __syncthreads();
    }
    if (tid == 0) out[0] = -logf(red[0] * (1.f / 1024.f) + EPSF);
}

// =====================================================================
extern "C" void kernel_launch(void* const* d_in, const int* in_sizes, int n_in,
                              void* d_out, int out_size, void* d_ws, size_t ws_size,
                              hipStream_t stream) {
    const float* x    = (const float*)d_in[0];   // (32,128,512)
    const float* cent = (const float*)d_in[1];   // (512, 128*512)
    float* out = (float*)d_out;
    float* ws  = (float*)d_ws;

    float* Cp     = ws + NWS_CP;
    float* part   = ws + NWS_PART;
    float* normsq = ws + NWS_NSQ;
    float* hsic   = ws + NWS_HSIC;
    int*   ids    = (int*)(ws + NWS_IDS);

    gram_nb<<<NM, 256, 0, stream>>>(x, cent, Cp, normsq);
    hsic_partial<<<16 * NCH, 256, 0, stream>>>(Cp, part);
    combine_loss<<<BB, 256, 0, stream>>>(part, normsq, hsic, ids, out);
    scalar_loss<<<1, 1024, 0, stream>>>(hsic, normsq, ids, out);
}